// Round 13
// baseline (112.918 us; speedup 1.0000x reference)
//
#include <hip/hip_runtime.h>

// VectorQuantizer: z (32,64,64,64) fp32, codebook (1024,64) fp32.
// out = [z_q_st flat (8388608), vq_loss (1)]  (fp32)
// R21: R20 (i8, half the MFMA pipe) gave dur == R14 exactly -> kernel compute
// pipes don't set dur; phases are serial per block and 1 block/CU means no
// cross-block overlap (R12: 2x70KB blocks don't co-reside). This round: keep
// i8 sweep but stage HALF the codebook (32 KB) and sweep in TWO passes ->
// LDS ~37.5 KB -> 512-thr blocks co-reside 2/CU with slack; staggered blocks
// overlap quantize/z-load/epilogue with the other block's sweep. Argmax
// carries across halves in registers (tags hold global j). Epilogue gathers
// the ORIGINAL fp32 codebook row from L2 (cb_lds holds only half 1) -> z_q
// exact. Scoring identical to R20. Shell: memset(4B) + 1 kernel.

constexpr int DIM    = 64;
constexpr int NCODES = 1024;
constexpr int HWSZ   = 4096;     // 64*64
constexpr int NPOS   = 131072;   // 32*4096
constexpr int BLOCK  = 512;      // 8 waves
constexpr int PPB    = 256;      // 8 waves * 2 sets * 16 rows
constexpr int GRID   = NPOS / PPB;   // 512 = 2 blocks/CU (37.5 KB LDS each)
constexpr int HALF   = 512;      // codebook rows per staging pass
constexpr int CIP    = 68;       // T-table LDS row stride (pad: banks 2-way)

typedef float    f32x4  __attribute__((ext_vector_type(4)));
typedef int      int4v  __attribute__((ext_vector_type(4)));
typedef unsigned uint4v __attribute__((ext_vector_type(4)));

__global__ __launch_bounds__(BLOCK, 4) void vq_all(const float* __restrict__ z,
                                                   const float* __restrict__ cb,
                                                   float* __restrict__ out) {
    __shared__ __align__(16) unsigned char cb_lds[HALF * DIM];     // 32 KB i8
    __shared__ int   cinit_lds[16 * CIP];                          // 4.25 KB
    __shared__ int   bj_lds[PPB];                                  // 1 KB
    __shared__ float ls_lds[BLOCK / 64];

    const int tid  = threadIdx.x;
    const int w    = tid >> 6;        // wave 0..7
    const int lane = tid & 63;
    const int q    = lane >> 4;       // quad 0..3  (K-slice selector)
    const int r    = lane & 15;
    const int p0   = blockIdx.x * PPB;
    const int b    = p0 >> 12;
    const int hwb  = p0 & 4095;

    // ---- Quantize one codebook half into LDS: local row = tid, global row
    // j = h*512 + tid -> i8(65536*e). Unit u = channels 16u..16u+15 at slot
    // u ^ (j&3) ^ ((j>>2)&1)  (offset 512 preserves low bits). T-table entry
    // (j&15)*CIP + (j>>4) = (Cj<<10) + (1023-j). ----
    auto QUANT = [&](int h) {
        const int j = h * HALF + tid;
        const float4* src = (const float4*)(cb + (size_t)j * DIM);
        unsigned words[16];
        int nq = 0;
#pragma unroll
        for (int w4 = 0; w4 < 16; w4++) {
            float4 v = src[w4];
            int i0 = __float2int_rn(v.x * 65536.f);
            int i1 = __float2int_rn(v.y * 65536.f);
            int i2 = __float2int_rn(v.z * 65536.f);
            int i3 = __float2int_rn(v.w * 65536.f);
            nq += i0 * i0 + i1 * i1 + i2 * i2 + i3 * i3;
            words[w4] = (unsigned)((i0 & 255) | ((i1 & 255) << 8)
                                 | ((i2 & 255) << 16) | (i3 << 24));
        }
        const int Cj = 262144 - ((nq + 4096) >> 13);   // bias - round(|e|^2/8192)
        const int sswz = (j & 3) ^ ((j >> 2) & 1);
#pragma unroll
        for (int u = 0; u < 4; u++) {     // static words[] indices (no scratch)
            int us = u ^ sswz;
            uint4v tq = {words[4 * u], words[4 * u + 1],
                         words[4 * u + 2], words[4 * u + 3]};
            *(uint4v*)&cb_lds[(size_t)tid * 64 + us * 16] = tq;
        }
        cinit_lds[(j & 15) * CIP + (j >> 4)] = (Cj << 10) + (1023 - j);
    };

    QUANT(0);

    // ---- A fragments (i8) for both position sets (overlaps quantize) ----
    // Set s covers positions p0 + w*32 + s*16 + r; lane holds
    // A[row=r][k = q*16 + i], i = 0..15 (16 consecutive channels).
    int4v afragI[2];
    float zsq[2];
#pragma unroll
    for (int s = 0; s < 2; s++) {
        const float* zb = z + (size_t)b * DIM * HWSZ + hwb + w * 32 + s * 16 + r;
        float sq = 0.f;
        unsigned dw[4];
#pragma unroll
        for (int d = 0; d < 4; d++) {
            float v0 = zb[(size_t)(q * 16 + 4 * d + 0) * HWSZ];
            float v1 = zb[(size_t)(q * 16 + 4 * d + 1) * HWSZ];
            float v2 = zb[(size_t)(q * 16 + 4 * d + 2) * HWSZ];
            float v3 = zb[(size_t)(q * 16 + 4 * d + 3) * HWSZ];
            sq = fmaf(v0, v0, sq); sq = fmaf(v1, v1, sq);
            sq = fmaf(v2, v2, sq); sq = fmaf(v3, v3, sq);
            int i0 = __float2int_rn(v0 * 16.f);
            int i1 = __float2int_rn(v1 * 16.f);
            int i2 = __float2int_rn(v2 * 16.f);
            int i3 = __float2int_rn(v3 * 16.f);
            dw[d] = (unsigned)((i0 & 255) | ((i1 & 255) << 8)
                             | ((i2 & 255) << 16) | (i3 << 24));
        }
        int4v af = {(int)dw[0], (int)dw[1], (int)dw[2], (int)dw[3]};
        afragI[s] = af;
        sq += __shfl_xor(sq, 16, 64);   // sum K-slices -> exact |z_row|^2
        sq += __shfl_xor(sq, 32, 64);
        zsq[s] = sq;
    }

    __syncthreads();   // half 0 + its T entries staged

    // B base: loop-invariant per lane (j&3==r&3, (j>>2)&1==(r>>2)&1).
    const int bbase = r * 64 + ((q ^ (r & 3) ^ ((r >> 2) & 1)) * 16);

    unsigned best0[4], best1[4], tmp0[4], tmp1[4];
#pragma unroll
    for (int g = 0; g < 4; g++) { best0[g] = 0u; best1[g] = 0u; }

    int4v Bp[4];
    int4v Tq[2];
    const int4v cz = {0, 0, 0, 0};
    int4v accR[3][2];   // [jt%3][set]

    auto ISSUE = [&](int jt) {
        const int slot = jt & 3;
        int4v B = Bp[slot];
        accR[jt % 3][0] = __builtin_amdgcn_mfma_i32_16x16x64_i8(
            afragI[0], B, cz, 0, 0, 0);
        accR[jt % 3][1] = __builtin_amdgcn_mfma_i32_16x16x64_i8(
            afragI[1], B, cz, 0, 0, 0);
        // refill this B slot for jt+4 within the staged half (imm offset)
        Bp[slot] = *(const int4v*)&cb_lds[(((jt + 4) & 31) * 1024) + bbase];
    };

    auto PROCESS = [&](int pj) {
        const unsigned Tl = (unsigned)Tq[(pj >> 2) & 1][pj & 3];
#pragma unroll
        for (int g = 0; g < 4; g++) {
            // bits = ((dot + Cj) << 10) + (1023 - j): one v_lshl_add_u32
            unsigned b0 = ((unsigned)accR[pj % 3][0][g] << 10) + Tl;
            unsigned b1 = ((unsigned)accR[pj % 3][1][g] << 10) + Tl;
            if ((pj & 1) == 0) {
                tmp0[g] = b0; tmp1[g] = b1;                // stage even jt
            } else {
                unsigned m0 = tmp0[g] > b0 ? tmp0[g] : b0; // v_max3_u32
                unsigned m1 = tmp1[g] > b1 ? tmp1[g] : b1;
                best0[g] = best0[g] > m0 ? best0[g] : m0;
                best1[g] = best1[g] > m1 ? best1[g] : m1;
            }
        }
        if ((pj & 3) == 3)   // refill T half for column group (pj>>2)+2
            Tq[(pj >> 2) & 1] =
                *(const int4v*)&cinit_lds[r * CIP + ((((pj >> 2) + 2) & 15) * 4)];
    };

    // ---- Pass 0: rows 0..511 (jt 0..31), full ring drain ----
    Bp[0] = *(const int4v*)&cb_lds[0 * 1024 + bbase];
    Bp[1] = *(const int4v*)&cb_lds[1 * 1024 + bbase];
    Bp[2] = *(const int4v*)&cb_lds[2 * 1024 + bbase];
    Bp[3] = *(const int4v*)&cb_lds[3 * 1024 + bbase];
    Tq[0] = *(const int4v*)&cinit_lds[r * CIP + 0];
    Tq[1] = *(const int4v*)&cinit_lds[r * CIP + 4];

    ISSUE(0);
    ISSUE(1);
#pragma unroll
    for (int jt = 2; jt < 32; jt++) {
        ISSUE(jt);
        PROCESS(jt - 2);
    }
    PROCESS(30);
    PROCESS(31);

    __syncthreads();   // all waves done reading half 0
    QUANT(1);          // overwrite LDS with rows 512..1023 + T cols 32..63
    __syncthreads();   // half 1 staged

    // ---- Pass 1: rows 512..1023 (jt 32..63), re-primed B and T ----
    Bp[0] = *(const int4v*)&cb_lds[0 * 1024 + bbase];
    Bp[1] = *(const int4v*)&cb_lds[1 * 1024 + bbase];
    Bp[2] = *(const int4v*)&cb_lds[2 * 1024 + bbase];
    Bp[3] = *(const int4v*)&cb_lds[3 * 1024 + bbase];
    Tq[0] = *(const int4v*)&cinit_lds[r * CIP + 32];
    Tq[1] = *(const int4v*)&cinit_lds[r * CIP + 36];

    ISSUE(32);
    ISSUE(33);
#pragma unroll
    for (int jt = 34; jt < 64; jt++) {
        ISSUE(jt);
        PROCESS(jt - 2);
    }
    PROCESS(62);
    PROCESS(63);

    // ---- Column-argmax reduce over the 16 j-lanes of each quad ----
    unsigned bestu0[4], bestu1[4];
#pragma unroll
    for (int g = 0; g < 4; g++) {
        unsigned v0 = best0[g];
        unsigned v1 = best1[g];
#pragma unroll
        for (int off = 1; off < 16; off <<= 1) {
            unsigned w0 = (unsigned)__shfl_xor((int)v0, off, 64);
            unsigned w1 = (unsigned)__shfl_xor((int)v1, off, 64);
            v0 = v0 > w0 ? v0 : w0;
            v1 = v1 > w1 ? v1 : w1;
        }
        bestu0[g] = v0; bestu1[g] = v1;
    }

    // Writer lane for row m=r: quad q == r>>2 holds best for g == r&3.
    float lsum = 0.f;
    if (q == (r >> 2)) {
        int g = r & 3;
        unsigned v0 = bestu0[0], v1 = bestu1[0];
        v0 = (g == 1) ? bestu0[1] : v0;  v1 = (g == 1) ? bestu1[1] : v1;
        v0 = (g == 2) ? bestu0[2] : v0;  v1 = (g == 2) ? bestu1[2] : v1;
        v0 = (g == 3) ? bestu0[3] : v0;  v1 = (g == 3) ? bestu1[3] : v1;
        bj_lds[w * 32 + r]      = 1023 - (int)(v0 & 1023u);
        bj_lds[w * 32 + 16 + r] = 1023 - (int)(v1 & 1023u);
        // dist = |z|^2 + (262144 - score)/2^19   (score = bits >> 10)
        lsum = zsq[0] + (float)(262144 - (int)(v0 >> 10)) * (1.f / 524288.f)
             + zsq[1] + (float)(262144 - (int)(v1 >> 10)) * (1.f / 524288.f);
    }
#pragma unroll
    for (int off = 32; off > 0; off >>= 1) lsum += __shfl_down(lsum, off, 64);
    if (lane == 0) ls_lds[w] = lsum;
    __syncthreads();   // publish bj + ls
    if (tid == 0) {
        float s = 0.f;
#pragma unroll
        for (int i = 0; i < BLOCK / 64; i++) s += ls_lds[i];
        // loss partial: one device-scope atomic per block (512 total)
        atomicAdd(out + (size_t)NPOS * DIM, s * (1.25f / 8388608.f));
    }

    // ---- Epilogue: gather ORIGINAL fp32 codebook rows from L2 (exact z_q),
    // scatter NCHW; 64 consecutive positions per store instr. ----
    {
        int posi = tid & 255;            // position within the 256-pos block
        int uu   = tid >> 8;             // 0 or 1: units {uu, uu+2}
        int myj  = bj_lds[posi];
        float* ob = out + (size_t)b * DIM * HWSZ + hwb + posi;
#pragma unroll
        for (int k = 0; k < 2; k++) {
            int u = uu + 2 * k;          // unit -> channels 16u..16u+15
            const float4* crow = (const float4*)(cb + (size_t)myj * 64 + u * 16);
            float4 c0 = crow[0], c1 = crow[1], c2 = crow[2], c3 = crow[3];
            ob[(size_t)(u * 16 +  0) * HWSZ] = c0.x;
            ob[(size_t)(u * 16 +  1) * HWSZ] = c0.y;
            ob[(size_t)(u * 16 +  2) * HWSZ] = c0.z;
            ob[(size_t)(u * 16 +  3) * HWSZ] = c0.w;
            ob[(size_t)(u * 16 +  4) * HWSZ] = c1.x;
            ob[(size_t)(u * 16 +  5) * HWSZ] = c1.y;
            ob[(size_t)(u * 16 +  6) * HWSZ] = c1.z;
            ob[(size_t)(u * 16 +  7) * HWSZ] = c1.w;
            ob[(size_t)(u * 16 +  8) * HWSZ] = c2.x;
            ob[(size_t)(u * 16 +  9) * HWSZ] = c2.y;
            ob[(size_t)(u * 16 + 10) * HWSZ] = c2.z;
            ob[(size_t)(u * 16 + 11) * HWSZ] = c2.w;
            ob[(size_t)(u * 16 + 12) * HWSZ] = c3.x;
            ob[(size_t)(u * 16 + 13) * HWSZ] = c3.y;
            ob[(size_t)(u * 16 + 14) * HWSZ] = c3.z;
            ob[(size_t)(u * 16 + 15) * HWSZ] = c3.w;
        }
    }
}

extern "C" void kernel_launch(void* const* d_in, const int* in_sizes, int n_in,
                              void* d_out, int out_size, void* d_ws, size_t ws_size,
                              hipStream_t stream) {
    const float* z  = (const float*)d_in[0];
    const float* cb = (const float*)d_in[1];
    float* out = (float*)d_out;

    // zero the loss accumulator (graph-capturable async memset), then one kernel
    hipMemsetAsync(out + (size_t)NPOS * DIM, 0, sizeof(float), stream);
    vq_all<<<GRID, BLOCK, 0, stream>>>(z, cb, out);
}